// Round 3
// baseline (3875.417 us; speedup 1.0000x reference)
//
#include <hip/hip_runtime.h>

// Problem constants
#define B_ 256
#define T_ 512
#define F_ 256
#define H_ 512
#define E_ 128

#define FLAG_STRIDE 4   // ints (16 B) between per-block flags

typedef __bf16 bf16x8 __attribute__((ext_vector_type(8)));
typedef float f32x4 __attribute__((ext_vector_type(4)));

__device__ __forceinline__ unsigned short f2bf(float f) {
    unsigned u = __float_as_uint(f);
    u += 0x7FFFu + ((u >> 16) & 1u);   // round-to-nearest-even
    return (unsigned short)(u >> 16);
}
__device__ __forceinline__ float bf2f(unsigned short s) {
    return __uint_as_float(((unsigned)s) << 16);
}
__device__ __forceinline__ float sigm(float x) {
    return 1.f / (1.f + __expf(-x));
}
__device__ __forceinline__ float tanh_f(float x) {
    return 2.f / (1.f + __expf(-2.f * x)) - 1.f;
}

// ---------------- prep kernels ----------------

// x fp32 -> bf16, 4 elements/thread
__global__ void cvt_x(const float* __restrict__ x, unsigned short* __restrict__ xb) {
    int i = blockIdx.x * 256 + threadIdx.x;       // 8,388,608 threads exactly
    float4 v = ((const float4*)x)[i];
    ushort4 o;
    o.x = f2bf(v.x); o.y = f2bf(v.y); o.z = f2bf(v.z); o.w = f2bf(v.w);
    ((ushort4*)xb)[i] = o;
}

// Build fragment-major weight array Wf (bf16) and permuted bias bp[2048].
// Wf[((idx*48 + fi)*64 + lane)*8 + j], fi = kt*2 + nt (kt 0..23 K-chunks, nt n-tile).
// Fragment element: B[n = nt*16 + (lane&15)][k = kt*32 + (lane>>4)*8 + j]
// for block idx's permuted gate rows; permuted row nl -> original gate row
// orow = (nl>>3)*512 + idx*8 + (nl&7)  (i/f/g/o gate quarters of 8 cols each).
__global__ void prep_w(const float* __restrict__ Wih, const float* __restrict__ Whh,
                       const float* __restrict__ bih, const float* __restrict__ bhh,
                       unsigned short* __restrict__ Wf, float* __restrict__ bp) {
    int gid = blockIdx.x * 256 + threadIdx.x;     // 1,572,864 threads exactly
    int j = gid & 7;
    int o = gid >> 3;
    int lane = o & 63;
    o >>= 6;
    int fi  = o % 48;
    int idx = o / 48;
    int kt = fi >> 1, nt = fi & 1;
    int l16 = lane & 15, quad = lane >> 4;
    int nl = nt * 16 + l16;
    int orow = (nl >> 3) * 512 + idx * 8 + (nl & 7);
    int k = kt * 32 + quad * 8 + j;
    float v = (k < 256) ? Wih[orow * 256 + k] : Whh[orow * 512 + (k - 256)];
    Wf[gid] = f2bf(v);
    if (kt == 0 && quad == 0 && j == 0)
        bp[idx * 32 + nl] = bih[orow] + bhh[orow];
}

// h0 fp32 -> bf16 into parity-0 h buffer; zero the per-block flags
__global__ void init_hb(const float* __restrict__ h0, unsigned short* __restrict__ hbuf,
                        int* __restrict__ flags) {
    int i = blockIdx.x * 256 + threadIdx.x;       // 131,072 threads exactly
    hbuf[i] = f2bf(h0[i]);
    if (i < 4 * 64 * FLAG_STRIDE) flags[i] = 0;
}

// ---------------- persistent LSTM kernel (cooperative) ----------------
// grid = 256 blocks x 256 threads, 1 block/CU. cluster = bid>>6 (64 batch rows),
// idx = bid&63 (8 h-cols -> 32 permuted gate rows). ALL weights register-resident
// (48 B-fragments = 192 VGPRs/lane, loaded once). Cell state thread-private.
// Sync: per-block monotonic flags; wave0 polls all 64 in parallel. h exchange via
// agent-scope relaxed atomics (write-through / L1-L2-bypassing, IF$-coherent).
__global__ void __launch_bounds__(256, 1) lstm_kernel(
        const unsigned short* __restrict__ xb,   // [B][T][F] bf16
        const unsigned short* __restrict__ Wf,   // fragment-major weights
        const float* __restrict__ bp,            // [2048] permuted bias
        const float* __restrict__ c0,            // [B][H] fp32
        unsigned short* __restrict__ hbuf,       // [2][B][H] bf16
        int* __restrict__ flags) {               // [4][64] padded step flags

    __shared__ float gl[64][33];                 // gate staging, +1 pad

    const int tid = threadIdx.x;
    const int bid = blockIdx.x;
    const int cluster = bid >> 6;
    const int idx = bid & 63;
    const int m0 = cluster * 64;     // first batch row of cluster
    const int j0 = idx * 8;          // first h-col owned by this block
    const int gr0 = idx * 32;        // first permuted gate row

    const int lane = tid & 63;
    const int wave = tid >> 6;
    const int l16  = lane & 15;
    const int quad = lane >> 4;
    const int am   = m0 + wave * 16 + l16;   // this lane's A-row (global batch row)

    // ---- weights -> registers, once (48 fragments x 16 B / lane)
    bf16x8 wr[48];
    {
        const bf16x8* wsrc = (const bf16x8*)Wf + ((size_t)idx * 48) * 64 + lane;
        #pragma unroll
        for (int fi = 0; fi < 48; ++fi)
            wr[fi] = wsrc[fi * 64];
    }

    const float b0 = bp[gr0 + l16];          // bias, n-tile 0 (i,f)
    const float b1 = bp[gr0 + 16 + l16];     // bias, n-tile 1 (g,o)

    // elementwise coords: thread owns 2 consecutive h/c cols, c thread-private
    const int em = tid >> 2;                 // 0..63  local batch row
    const int ej = (tid & 3) * 2;            // 0,2,4,6 local col pair
    float cr0 = c0[(size_t)(m0 + em) * H_ + j0 + ej];
    float cr1 = c0[(size_t)(m0 + em) * H_ + j0 + ej + 1];

    int* const clflags  = flags + cluster * 64 * FLAG_STRIDE;
    int* const ownflag  = clflags + idx * FLAG_STRIDE;
    int* const pollflag = clflags + lane * FLAG_STRIDE;  // wave0: lane <-> block

    for (int t = 0; t < T_; ++t) {
        const int par = t & 1;
        const unsigned short* hsrc = hbuf + (size_t)par * (B_ * H_);
        unsigned short* hdst = hbuf + (size_t)(par ^ 1) * (B_ * H_);

        f32x4 acc0 = {b0, b0, b0, b0};
        f32x4 acc1 = {b1, b1, b1, b1};

        // ---- x-part (K = 0..256): independent of h -> before the wait
        {
            const unsigned short* xr =
                xb + (size_t)am * (T_ * F_) + (size_t)t * F_ + quad * 8;
            #pragma unroll
            for (int kt = 0; kt < 8; ++kt) {
                bf16x8 a = *(const bf16x8*)(xr + kt * 32);
                acc0 = __builtin_amdgcn_mfma_f32_16x16x32_bf16(a, wr[2 * kt],     acc0, 0, 0, 0);
                acc1 = __builtin_amdgcn_mfma_f32_16x16x32_bf16(a, wr[2 * kt + 1], acc1, 0, 0, 0);
            }
        }

        // ---- wait: all 64 producer flags >= t (h_t fully published)
        if (t > 0) {
            if (wave == 0) {
                for (;;) {
                    int v = __hip_atomic_load(pollflag, __ATOMIC_RELAXED,
                                              __HIP_MEMORY_SCOPE_AGENT);
                    if (__all(v >= t)) break;
                    __builtin_amdgcn_s_sleep(1);
                }
            }
            __syncthreads();
        }

        // ---- h-part (K = 256..768); weights in regs, loads IF$-coherent
        {
            const unsigned long long* hq = (const unsigned long long*)hsrc +
                (((size_t)am * H_ + quad * 8) >> 2);
            #pragma unroll
            for (int kt = 0; kt < 16; ++kt) {
                union { unsigned long long q[2]; bf16x8 v; } ha;
                ha.q[0] = __hip_atomic_load(hq + kt * 8,     __ATOMIC_RELAXED,
                                            __HIP_MEMORY_SCOPE_AGENT);
                ha.q[1] = __hip_atomic_load(hq + kt * 8 + 1, __ATOMIC_RELAXED,
                                            __HIP_MEMORY_SCOPE_AGENT);
                acc0 = __builtin_amdgcn_mfma_f32_16x16x32_bf16(ha.v, wr[16 + 2 * kt],     acc0, 0, 0, 0);
                acc1 = __builtin_amdgcn_mfma_f32_16x16x32_bf16(ha.v, wr[16 + 2 * kt + 1], acc1, 0, 0, 0);
            }
        }

        // ---- epilogue: C-layout (col=lane&15, row=quad*4+reg) -> LDS
        #pragma unroll
        for (int r = 0; r < 4; ++r) {
            gl[wave * 16 + quad * 4 + r][l16]      = acc0[r];
            gl[wave * 16 + quad * 4 + r][16 + l16] = acc1[r];
        }
        __syncthreads();

        // elementwise gates; local n layout [i(8) f(8) g(8) o(8)]; c in VGPRs
        {
            float i0 = sigm(gl[em][ej]);
            float i1 = sigm(gl[em][ej + 1]);
            float f0 = sigm(gl[em][ej + 8]);
            float f1 = sigm(gl[em][ej + 9]);
            float g0 = tanh_f(gl[em][ej + 16]);
            float g1 = tanh_f(gl[em][ej + 17]);
            float o0 = sigm(gl[em][ej + 24]);
            float o1 = sigm(gl[em][ej + 25]);
            cr0 = f0 * cr0 + i0 * g0;
            cr1 = f1 * cr1 + i1 * g1;
            float h0v = o0 * tanh_f(cr0);
            float h1v = o1 * tanh_f(cr1);
            unsigned pack = (unsigned)f2bf(h0v) | ((unsigned)f2bf(h1v) << 16);
            unsigned* dst = (unsigned*)hdst +
                (((size_t)(m0 + em) * H_ + j0 + ej) >> 1);
            __hip_atomic_store(dst, pack, __ATOMIC_RELAXED,
                               __HIP_MEMORY_SCOPE_AGENT);
        }
        __syncthreads();   // drains vmcnt in every wave -> h globally visible
        if (tid == 0)
            __hip_atomic_store(ownflag, t + 1, __ATOMIC_RELAXED,
                               __HIP_MEMORY_SCOPE_AGENT);
    }
}

// ---------------- FC head ----------------
__global__ void fc_kernel(const unsigned short* __restrict__ hT,
                          const float* __restrict__ Wfc,
                          const float* __restrict__ bfc,
                          float* __restrict__ out) {
    __shared__ float hs[512];
    int m = blockIdx.x;
    for (int k = threadIdx.x; k < 512; k += 128)
        hs[k] = bf2f(hT[(size_t)m * 512 + k]);
    __syncthreads();
    int e = threadIdx.x;
    const float4* w4 = (const float4*)(Wfc + (size_t)e * 512);
    float s = bfc[e];
    #pragma unroll 8
    for (int k4 = 0; k4 < 128; ++k4) {
        float4 w = w4[k4];
        s += hs[4 * k4] * w.x + hs[4 * k4 + 1] * w.y +
             hs[4 * k4 + 2] * w.z + hs[4 * k4 + 3] * w.w;
    }
    out[(size_t)m * 128 + e] = 1.f / (1.f + __expf(-s));
}

// ---------------- launch ----------------
extern "C" void kernel_launch(void* const* d_in, const int* in_sizes, int n_in,
                              void* d_out, int out_size, void* d_ws, size_t ws_size,
                              hipStream_t stream) {
    const float* x   = (const float*)d_in[0];
    const float* h0  = (const float*)d_in[1];
    const float* c0  = (const float*)d_in[2];
    const float* Wih = (const float*)d_in[3];
    const float* Whh = (const float*)d_in[4];
    const float* bih = (const float*)d_in[5];
    const float* bhh = (const float*)d_in[6];
    const float* Wfc = (const float*)d_in[7];
    const float* bfc = (const float*)d_in[8];
    float* out = (float*)d_out;

    // ws layout (~67.6 MiB)
    char* w = (char*)d_ws;
    unsigned short* xb = (unsigned short*)(w);                  // 67,108,864 B
    unsigned short* Wf = (unsigned short*)(w + 67108864);       //  3,145,728 B
    float*          bp = (float*)(w + 70254592);                //      8,192 B
    unsigned short* hb = (unsigned short*)(w + 70262784);       //    524,288 B
    int*         flags = (int*)(w + 70787072);                  //      4,096 B

    cvt_x  <<<32768, 256, 0, stream>>>(x, xb);
    prep_w <<<6144,  256, 0, stream>>>(Wih, Whh, bih, bhh, Wf, bp);
    init_hb<<<512,   256, 0, stream>>>(h0, hb, flags);

    void* args[6];
    args[0] = (void*)&xb;
    args[1] = (void*)&Wf;
    args[2] = (void*)&bp;
    args[3] = (void*)&c0;
    args[4] = (void*)&hb;
    args[5] = (void*)&flags;
    hipLaunchCooperativeKernel((const void*)lstm_kernel, dim3(256), dim3(256),
                               args, 0, stream);

    // T=512 even -> final h lives in parity-0 buffer
    fc_kernel<<<256, 128, 0, stream>>>(hb, Wfc, bfc, out);
}

// Round 6
// 2568.172 us; speedup vs baseline: 1.5090x; 1.5090x over previous
//
#include <hip/hip_runtime.h>

// Problem constants
#define B_ 256
#define T_ 512
#define F_ 256
#define H_ 512
#define E_ 128

#define FLAG_STRIDE 4   // ints (16 B) between per-block flags

typedef __bf16 bf16x8 __attribute__((ext_vector_type(8)));
typedef float f32x4 __attribute__((ext_vector_type(4)));

__device__ __forceinline__ unsigned short f2bf(float f) {
    unsigned u = __float_as_uint(f);
    u += 0x7FFFu + ((u >> 16) & 1u);   // round-to-nearest-even
    return (unsigned short)(u >> 16);
}
__device__ __forceinline__ float bf2f(unsigned short s) {
    return __uint_as_float(((unsigned)s) << 16);
}
__device__ __forceinline__ float sigm(float x) {
    return 1.f / (1.f + __expf(-x));
}
__device__ __forceinline__ float tanh_f(float x) {
    return 2.f / (1.f + __expf(-2.f * x)) - 1.f;
}

// ---------------- prep kernels ----------------

// x fp32 -> bf16, 4 elements/thread (33,554,432 elements total)
__global__ void cvt_x(const float* __restrict__ x, unsigned short* __restrict__ xb) {
    int i = blockIdx.x * 256 + threadIdx.x;
    float4 v = ((const float4*)x)[i];
    ushort4 o;
    o.x = f2bf(v.x); o.y = f2bf(v.y); o.z = f2bf(v.z); o.w = f2bf(v.w);
    ((ushort4*)xb)[i] = o;
}

// Fragment-major weights for the 8x32 geometry.
// Wf bf16x8 index: (idx*96 + fi)*64 + lane, fi = kt*4 + nt (kt 0..23, nt 0..3).
// Fragment element j: B[n = nt*16 + l16][k = kt*32 + quad*8 + j] for block idx,
// gate-row n -> original row orow = nt*512 + idx*16 + l16.
__global__ void prep_w(const float* __restrict__ Wih, const float* __restrict__ Whh,
                       const float* __restrict__ bih, const float* __restrict__ bhh,
                       unsigned short* __restrict__ Wf, float* __restrict__ bp) {
    int gid = blockIdx.x * 256 + threadIdx.x;     // 1,572,864 threads exactly
    int j = gid & 7;
    int rest = gid >> 3;
    int lane = rest & 63;
    rest >>= 6;                 // idx*96 + fi
    int fi  = rest % 96;
    int idx = rest / 96;
    int kt = fi >> 2, nt = fi & 3;
    int l16 = lane & 15, quad = lane >> 4;
    int orow = nt * 512 + idx * 16 + l16;
    int k = kt * 32 + quad * 8 + j;
    float v = (k < 256) ? Wih[orow * 256 + k] : Whh[orow * 512 + (k - 256)];
    Wf[gid] = f2bf(v);
    if (k == 0 && j == 0)
        bp[idx * 64 + nt * 16 + l16] = bih[orow] + bhh[orow];
}

// h0 fp32 -> bf16 into parity-0 h buffer; zero the flags
__global__ void init_hb(const float* __restrict__ h0, unsigned short* __restrict__ hbuf,
                        int* __restrict__ flags) {
    int i = blockIdx.x * 256 + threadIdx.x;       // 131,072 threads exactly
    hbuf[i] = f2bf(h0[i]);
    if (i < 8 * 32 * FLAG_STRIDE) flags[i] = 0;
}

// ---------------- persistent LSTM kernel (cooperative) ----------------
// grid = 256 x 256, 1 block/CU. cluster = bid & 7 (XCD-affine under round-robin
// dispatch), idx = bid >> 3. Cluster owns batch rows [cluster*32,+32); block
// owns h-cols [idx*16,+16) => 64 gate rows = 4 n-tiles. Weights register-resident.
//
// FAST mode (runtime-verified: whole cluster on one XCD): the LLVM tgsplit
// coherence idiom for CUs sharing an L2 —
//   producer: plain write-through stores, vmcnt drained at barrier, plain flag;
//   consumer: buffer_inv sc0 (invalidate CU-private L1 ONLY; cheap) then PLAIN
//   loads -> must refill from the shared per-XCD L2 which holds fresh data.
// No reliance on sc-bit load semantics; no inline-asm bulk loads (the R4/R5
// poll asm lacked early-clobber -> output could alias the address pair).
// SLOW mode: full agent-scope protocol via IF$ (R3-proven).
__global__ void __launch_bounds__(256, 1) lstm_kernel(
        const unsigned short* __restrict__ xb,   // [B][T][F] bf16
        const unsigned short* __restrict__ Wf,   // fragment-major weights
        const float* __restrict__ bp,            // [2048] permuted bias
        const float* __restrict__ c0,            // [B][H] fp32
        unsigned short* __restrict__ hbuf,       // [2][B][H] bf16
        int* __restrict__ flags) {               // [8][32] padded flags

    __shared__ float gl[32][68];                 // gate staging
    __shared__ int sh_fast;

    const int tid = threadIdx.x;
    const int bid = blockIdx.x;
    const int cluster = bid & 7;
    const int idx = bid >> 3;
    const int m0 = cluster * 32;     // first batch row of cluster
    const int j0 = idx * 16;         // first h-col owned by this block

    int myxcd;
    asm("s_getreg_b32 %0, hwreg(20, 0, 32)" : "=s"(myxcd));  // HW_REG_XCC_ID
    myxcd &= 15;

    const int lane = tid & 63;
    const int wave = tid >> 6;
    const int l16  = lane & 15;
    const int quad = lane >> 4;
    const int mt   = wave & 1;        // m-tile of this wave
    const int np   = wave >> 1;       // n-tile pair of this wave
    const int am   = m0 + mt * 16 + l16;   // this lane's A-row (global batch row)

    // ---- weights -> registers/AGPRs, once (48 fragments x 16 B / lane)
    bf16x8 wr[48];
    {
        const bf16x8* wsrc = (const bf16x8*)Wf;
        #pragma unroll
        for (int kt = 0; kt < 24; ++kt) {
            wr[kt * 2]     = wsrc[((size_t)idx * 96 + kt * 4 + 2 * np)     * 64 + lane];
            wr[kt * 2 + 1] = wsrc[((size_t)idx * 96 + kt * 4 + 2 * np + 1) * 64 + lane];
        }
    }

    const float b0 = bp[idx * 64 + (2 * np)     * 16 + l16];
    const float b1 = bp[idx * 64 + (2 * np + 1) * 16 + l16];

    // elementwise coords: thread owns 2 consecutive h/c cols, c thread-private
    const int em = tid >> 3;                 // 0..31  local batch row
    const int ej = (tid & 7) * 2;            // 0..14  local col pair
    float cr0 = c0[(size_t)(m0 + em) * H_ + j0 + ej];
    float cr1 = c0[(size_t)(m0 + em) * H_ + j0 + ej + 1];

    int* const ownflag = flags + (cluster * 32 + idx) * FLAG_STRIDE;
    int* const pollfp  = flags + (cluster * 32 + (lane & 31)) * FLAG_STRIDE;

    // ---- pre-loop handshake (agent scope): publish XCD stamp, decide mode ----
    if (tid == 0)
        __hip_atomic_store(ownflag, (1 << 8) | myxcd, __ATOMIC_RELAXED,
                           __HIP_MEMORY_SCOPE_AGENT);
    if (wave == 0) {
        int v;
        for (;;) {
            v = __hip_atomic_load(pollfp, __ATOMIC_RELAXED,
                                  __HIP_MEMORY_SCOPE_AGENT);
            if (__all((v >> 8) >= 1)) break;
            __builtin_amdgcn_s_sleep(1);
        }
        int f = __all((v & 255) == myxcd) ? 1 : 0;
        if (tid == 0) sh_fast = f;
    }
    __syncthreads();
    const int fast = sh_fast;

    for (int t = 0; t < T_; ++t) {
        const int par = t & 1;
        const unsigned short* hsrc = hbuf + (size_t)par * (B_ * H_);
        unsigned short* hdst = hbuf + (size_t)(par ^ 1) * (B_ * H_);

        f32x4 acc0 = {b0, b0, b0, b0};
        f32x4 acc1 = {b1, b1, b1, b1};

        // ---- x-part (K = 0..256): independent of h -> before the wait
        {
            const unsigned short* xr =
                xb + (size_t)am * (T_ * F_) + (size_t)t * F_ + quad * 8;
            #pragma unroll
            for (int kt = 0; kt < 8; ++kt) {
                bf16x8 a = *(const bf16x8*)(xr + kt * 32);
                acc0 = __builtin_amdgcn_mfma_f32_16x16x32_bf16(a, wr[2 * kt],     acc0, 0, 0, 0);
                acc1 = __builtin_amdgcn_mfma_f32_16x16x32_bf16(a, wr[2 * kt + 1], acc1, 0, 0, 0);
            }
        }

        // ---- wait: all 32 producer flags show step t-1 done ((v>>8) >= t+1)
        if (t > 0) {
            if (fast) {
                if (wave == 0) {
                    const unsigned long long fa = (unsigned long long)pollfp;
                    int v;
                    do {
                        // invalidate CU L1, then load flag (sc0: L2 lookup);
                        // "=&v" early-clobber: output must NOT alias fa pair
                        asm volatile("buffer_inv sc0\n\t"
                                     "global_load_dword %0, %1, off sc0\n\t"
                                     "s_waitcnt vmcnt(0)"
                                     : "=&v"(v) : "v"(fa) : "memory");
                    } while (!__all((v >> 8) >= t + 1));
                    // L1 now invalidated after the flag was observed: subsequent
                    // plain h loads (all waves, same CU-shared L1) refill from L2.
                }
                __syncthreads();
            } else {
                if (wave == 0) {
                    int v;
                    for (;;) {
                        v = __hip_atomic_load(pollfp, __ATOMIC_RELAXED,
                                              __HIP_MEMORY_SCOPE_AGENT);
                        if (__all((v >> 8) >= t + 1)) break;
                        __builtin_amdgcn_s_sleep(1);
                    }
                }
                __syncthreads();
            }
        }

        // ---- h-part (K = 256..768); weights in regs
        if (t == 0 || fast) {
            // plain loads: t==0 kernel-boundary coherent; fast mode L1 was
            // invalidated post-poll, so these refill from the fresh shared L2
            const unsigned short* hr = hsrc + (size_t)am * H_ + quad * 8;
            #pragma unroll
            for (int kt = 0; kt < 16; ++kt) {
                bf16x8 a = *(const bf16x8*)(hr + kt * 32);
                acc0 = __builtin_amdgcn_mfma_f32_16x16x32_bf16(a, wr[16 + 2 * kt],     acc0, 0, 0, 0);
                acc1 = __builtin_amdgcn_mfma_f32_16x16x32_bf16(a, wr[16 + 2 * kt + 1], acc1, 0, 0, 0);
            }
        } else {
            // cross-XCD fallback: agent-scope loads via IF$ (R3 path)
            const unsigned long long* hq = (const unsigned long long*)hsrc +
                (((size_t)am * H_ + quad * 8) >> 2);
            #pragma unroll
            for (int kt = 0; kt < 16; ++kt) {
                union { unsigned long long q[2]; bf16x8 v; } ha;
                ha.q[0] = __hip_atomic_load(hq + kt * 8,     __ATOMIC_RELAXED,
                                            __HIP_MEMORY_SCOPE_AGENT);
                ha.q[1] = __hip_atomic_load(hq + kt * 8 + 1, __ATOMIC_RELAXED,
                                            __HIP_MEMORY_SCOPE_AGENT);
                acc0 = __builtin_amdgcn_mfma_f32_16x16x32_bf16(ha.v, wr[16 + 2 * kt],     acc0, 0, 0, 0);
                acc1 = __builtin_amdgcn_mfma_f32_16x16x32_bf16(ha.v, wr[16 + 2 * kt + 1], acc1, 0, 0, 0);
            }
        }

        // ---- epilogue: C-layout (col=l16, row=quad*4+r) -> LDS gate staging
        #pragma unroll
        for (int r = 0; r < 4; ++r) {
            gl[mt * 16 + quad * 4 + r][(2 * np)     * 16 + l16] = acc0[r];
            gl[mt * 16 + quad * 4 + r][(2 * np + 1) * 16 + l16] = acc1[r];
        }
        __syncthreads();

        // elementwise gates; gate cols [i(16) f(16) g(16) o(16)]; c in VGPRs
        {
            float i0 = sigm(gl[em][ej]);
            float i1 = sigm(gl[em][ej + 1]);
            float f0 = sigm(gl[em][16 + ej]);
            float f1 = sigm(gl[em][16 + ej + 1]);
            float g0 = tanh_f(gl[em][32 + ej]);
            float g1 = tanh_f(gl[em][32 + ej + 1]);
            float o0 = sigm(gl[em][48 + ej]);
            float o1 = sigm(gl[em][48 + ej + 1]);
            cr0 = f0 * cr0 + i0 * g0;
            cr1 = f1 * cr1 + i1 * g1;
            float h0v = o0 * tanh_f(cr0);
            float h1v = o1 * tanh_f(cr1);
            unsigned pack = (unsigned)f2bf(h0v) | ((unsigned)f2bf(h1v) << 16);
            unsigned* dst = (unsigned*)hdst +
                (((size_t)(m0 + em) * H_ + j0 + ej) >> 1);
            if (fast) {
                *dst = pack;   // plain write-through -> lands in shared XCD L2
            } else {
                __hip_atomic_store(dst, pack, __ATOMIC_RELAXED,
                                   __HIP_MEMORY_SCOPE_AGENT);  // via IF$
            }
        }
        __syncthreads();   // every wave drains vmcnt -> h committed (L2 / IF$)
        if (tid == 0) {
            int fv = (t + 2) << 8;
            if (fast) {
                *(volatile int*)ownflag = fv;      // plain store into shared L2
            } else {
                __hip_atomic_store(ownflag, fv, __ATOMIC_RELAXED,
                                   __HIP_MEMORY_SCOPE_AGENT);
            }
        }
    }
}

// ---------------- FC head ----------------
// (kernel completion performs the device-scope release: dirty L2 lines are
// written back at end of lstm_kernel, so plain loads here are coherent)
__global__ void fc_kernel(const unsigned short* __restrict__ hT,
                          const float* __restrict__ Wfc,
                          const float* __restrict__ bfc,
                          float* __restrict__ out) {
    __shared__ float hs[512];
    int m = blockIdx.x;
    for (int k = threadIdx.x; k < 512; k += 128)
        hs[k] = bf2f(hT[(size_t)m * 512 + k]);
    __syncthreads();
    int e = threadIdx.x;
    const float4* w4 = (const float4*)(Wfc + (size_t)e * 512);
    float s = bfc[e];
    #pragma unroll 8
    for (int k4 = 0; k4 < 128; ++k4) {
        float4 w = w4[k4];
        s += hs[4 * k4] * w.x + hs[4 * k4 + 1] * w.y +
             hs[4 * k4 + 2] * w.z + hs[4 * k4 + 3] * w.w;
    }
    out[(size_t)m * 128 + e] = 1.f / (1.f + __expf(-s));
}

// ---------------- launch ----------------
extern "C" void kernel_launch(void* const* d_in, const int* in_sizes, int n_in,
                              void* d_out, int out_size, void* d_ws, size_t ws_size,
                              hipStream_t stream) {
    const float* x   = (const float*)d_in[0];
    const float* h0  = (const float*)d_in[1];
    const float* c0  = (const float*)d_in[2];
    const float* Wih = (const float*)d_in[3];
    const float* Whh = (const float*)d_in[4];
    const float* bih = (const float*)d_in[5];
    const float* bhh = (const float*)d_in[6];
    const float* Wfc = (const float*)d_in[7];
    const float* bfc = (const float*)d_in[8];
    float* out = (float*)d_out;

    // ws layout (~70.8 MiB)
    char* w = (char*)d_ws;
    unsigned short* xb = (unsigned short*)(w);                  // 67,108,864 B
    unsigned short* Wf = (unsigned short*)(w + 67108864);       //  3,145,728 B
    float*          bp = (float*)(w + 70254592);                //      8,192 B
    unsigned short* hb = (unsigned short*)(w + 70262784);       //    524,288 B
    int*         flags = (int*)(w + 70787072);                  //      4,096 B

    cvt_x  <<<32768, 256, 0, stream>>>(x, xb);
    prep_w <<<6144,  256, 0, stream>>>(Wih, Whh, bih, bhh, Wf, bp);
    init_hb<<<512,   256, 0, stream>>>(h0, hb, flags);

    void* args[6];
    args[0] = (void*)&xb;
    args[1] = (void*)&Wf;
    args[2] = (void*)&bp;
    args[3] = (void*)&c0;
    args[4] = (void*)&hb;
    args[5] = (void*)&flags;
    hipLaunchCooperativeKernel((const void*)lstm_kernel, dim3(256), dim3(256),
                               args, 0, stream);

    // T=512 even -> final h lives in parity-0 buffer
    fc_kernel<<<256, 128, 0, stream>>>(hb, Wfc, bfc, out);
}